// Round 6
// baseline (102.423 us; speedup 1.0000x reference)
//
#include <hip/hip_runtime.h>
#include <hip/hip_bf16.h>

#define BB 2
#define CC 320
#define HH 64
#define WW 128
#define MAXDISP 48
#define GG 40
#define CPG 8     // channels per group = C / G
#define CR 20     // C / R

typedef float fx4 __attribute__((ext_vector_type(4)));

// -------------------------------------------------------------------------
// Kernel A: GAP + fan-in CMCAM mask.
// 1280 blocks; block = (img, b, c) row. Each block reduces its row, stores
// the mean with an agent-scope atomic store, then bumps a device counter
// (acq-rel, agent scope). The LAST block to arrive (old == 1279) sees all
// row means (agent-scope loads bypass the non-coherent per-XCD L2) and runs
// the tiny FC stack, emitting fused weights:
//   alpha = m_ref*m_tgt/8,  beta = (1-m_ref)(1-m_tgt)/8   (/8 folds the
// group-mean of the volume kernel). No spin, no co-residency assumption.
// -------------------------------------------------------------------------
__global__ __launch_bounds__(256) void gap_mask_kernel(
    const float* __restrict__ ref, const float* __restrict__ tgt,
    const float* __restrict__ w1, const float* __restrict__ b1,
    const float* __restrict__ w2, const float* __restrict__ b2,
    float* __restrict__ gap /* [2][B][C] */,
    float* __restrict__ alpha, float* __restrict__ beta /* [B*C] */,
    unsigned* __restrict__ counter) {
  int bid = blockIdx.x;            // 0 .. 1280
  int img = bid / (BB * CC);       // 0/1
  int rc  = bid - img * (BB * CC); // b*C + c
  int tid = threadIdx.x;
  const float* src = (img ? tgt : ref) + (size_t)rc * (HH * WW);
  const float4* v = reinterpret_cast<const float4*>(src);
  float acc = 0.f;
  for (int i = tid; i < (HH * WW) / 4; i += 256) {
    float4 x = v[i];
    acc += (x.x + x.y) + (x.z + x.w);
  }
  for (int off = 32; off; off >>= 1) acc += __shfl_down(acc, off, 64);
  __shared__ float part[4];
  __shared__ int lastf;
  if ((tid & 63) == 0) part[tid >> 6] = acc;
  __syncthreads();
  if (tid == 0) {
    float s = (part[0] + part[1]) + (part[2] + part[3]);
    __hip_atomic_store(gap + bid, s * (1.0f / (HH * WW)),
                       __ATOMIC_RELAXED, __HIP_MEMORY_SCOPE_AGENT);
    unsigned old = __hip_atomic_fetch_add(counter, 1u, __ATOMIC_ACQ_REL,
                                          __HIP_MEMORY_SCOPE_AGENT);
    lastf = (old == 2 * BB * CC - 1);
  }
  __syncthreads();
  if (!lastf) return;

  // ---- last block: FC stack ----
  __shared__ float gs[2 * BB * CC];   // 1280
  __shared__ float hs[2 * BB * CR];   // 80
  __shared__ float ms[2 * BB * CC];   // 1280
  for (int i = tid; i < 2 * BB * CC; i += 256)
    gs[i] = __hip_atomic_load(gap + i, __ATOMIC_RELAXED,
                              __HIP_MEMORY_SCOPE_AGENT);
  __syncthreads();
  if (tid < 2 * 2 * BB * CR) {        // FC1: 80 dots of 320, 2 thr/dot
    int p = tid >> 1, half = tid & 1;
    int j = p % CR;
    int ib = p / CR;                  // img*B + b
    const float4* wrow = reinterpret_cast<const float4*>(w1 + j * CC);
    const float4* grow = reinterpret_cast<const float4*>(gs + ib * CC);
    float s = 0.f;
#pragma unroll 5
    for (int c = half * 40; c < half * 40 + 40; ++c) {
      float4 a = wrow[c], g = grow[c];
      s += a.x * g.x + a.y * g.y + a.z * g.z + a.w * g.w;
    }
    s += __shfl_xor(s, 1, 64);        // pair reduce (same wave)
    if (!half) {
      s += b1[j];
      hs[p] = s > 0.f ? s : 0.f;      // ReLU
    }
  }
  __syncthreads();
  for (int i = tid; i < 2 * BB * CC; i += 256) {  // FC2: 1280 dots of 20
    int c = i % CC;
    int ib = i / CC;
    float s = b2[c];
    const float* hrow = hs + ib * CR;
    const float* wrow = w2 + c * CR;
#pragma unroll
    for (int j = 0; j < CR; ++j) s += wrow[j] * hrow[j];
    ms[i] = 1.f / (1.f + expf(-s));   // sigmoid
  }
  __syncthreads();
  for (int i = tid; i < BB * CC; i += 256) {  // i = b*C + c
    float mr = ms[i];
    float mt = ms[BB * CC + i];
    alpha[i] = mr * mt * 0.125f;
    beta[i]  = (1.f - mr) * (1.f - mt) * 0.125f;
  }
}

// -------------------------------------------------------------------------
// Kernel B: both group-wise correlation volumes, register-ring version
// (unchanged from the 65.6 µs round).
// block = (b, g, h2). 256 threads = dslot(4) x hl(2) x w4(32).
// Thread owns 4 consecutive w (wq=4*w4) and 12 consecutive d (d0=12*dslot).
// Tap window slides by 1 per d-step -> 4-entry register ring per channel:
// 8 ds_read_b32 per step yield 8 outputs (2 float4 nt stores). LDS x-index
// XOR-swizzled (x ^ ((x>>5)&3)) to break the stride-4 8-way bank conflict;
// swizzle is within-16B so staging stays one permuted float4 write. Taps
// with x<0 are zeroed = the w<d zero region, no output masks.
// -------------------------------------------------------------------------
__global__ __launch_bounds__(256) void volume_kernel(
    const float* __restrict__ ref, const float* __restrict__ tgt,
    const float* __restrict__ alpha, const float* __restrict__ beta,
    float* __restrict__ out) {
  __shared__ float Tl[2][CPG][WW];   // 8 KB, x-swizzled
  int bid = blockIdx.x;              // b*(G*32) + g*32 + h2
  int b   = bid / (GG * 32);
  int rem = bid - b * (GG * 32);
  int g   = rem >> 5;
  int h2  = rem & 31;
  int tid = threadIdx.x;
  int dslot = tid >> 6;              // 0..3 (= wave id)
  int hl    = (tid >> 5) & 1;
  int w4    = tid & 31;
  int wq    = w4 << 2;
  int d0    = dslot * 12;
  int h     = h2 * 2 + hl;

  {
    int c_s = tid >> 5;
    int xq  = (tid & 31) << 2;
    int k   = (xq >> 5) & 3;         // swizzle key, constant over the quad
    size_t tb = ((size_t)((b * CC + g * CPG + c_s) * HH) + h2 * 2) * WW + xq;
    float4 v0 = *reinterpret_cast<const float4*>(tgt + tb);
    float4 v1 = *reinterpret_cast<const float4*>(tgt + tb + WW);
    float4 q0 = (k & 1) ? make_float4(v0.y, v0.x, v0.w, v0.z) : v0;
    q0 = (k & 2) ? make_float4(q0.z, q0.w, q0.x, q0.y) : q0;
    float4 q1 = (k & 1) ? make_float4(v1.y, v1.x, v1.w, v1.z) : v1;
    q1 = (k & 2) ? make_float4(q1.z, q1.w, q1.x, q1.y) : q1;
    *reinterpret_cast<float4*>(&Tl[0][c_s][xq]) = q0;
    *reinterpret_cast<float4*>(&Tl[1][c_s][xq]) = q1;
  }

  float rf[CPG][4];
  float al[CPG], be[CPG];
  size_t rbase = ((size_t)((b * CC + g * CPG) * HH) + h) * WW + wq;
#pragma unroll
  for (int c = 0; c < CPG; ++c) {
    float4 rv = *reinterpret_cast<const float4*>(ref + rbase + (size_t)c * (HH * WW));
    rf[c][0] = rv.x; rf[c][1] = rv.y; rf[c][2] = rv.z; rf[c][3] = rv.w;
    al[c] = alpha[b * CC + g * CPG + c];
    be[c] = beta[b * CC + g * CPG + c];
  }
  __syncthreads();

  const int A = wq - d0;
  float t[CPG][4];
#pragma unroll
  for (int r = 0; r < 4; ++r) {
    int x  = A + r;
    int xc = x < 0 ? 0 : x;
    int xs = xc ^ ((xc >> 5) & 3);
#pragma unroll
    for (int c = 0; c < CPG; ++c) {
      float v = Tl[hl][c][xs];
      t[c][r] = x < 0 ? 0.f : v;
    }
  }

  size_t o_hf = (((size_t)(b * 2 * GG + g) * MAXDISP + d0) * HH + h) * WW + wq;
  size_t o_ct = o_hf + (size_t)GG * MAXDISP * HH * WW;
#pragma unroll
  for (int i = 0; i < 12; ++i) {
    if (i > 0) {                     // slide window: new tap x = A - i
      int x  = A - i;
      int xc = x < 0 ? 0 : x;
      int xs = xc ^ ((xc >> 5) & 3);
      const int s = (16 - i) & 3;
#pragma unroll
      for (int c = 0; c < CPG; ++c) {
        float v = Tl[hl][c][xs];
        t[c][s] = x < 0 ? 0.f : v;
      }
    }
    float o0h = 0.f, o1h = 0.f, o2h = 0.f, o3h = 0.f;
    float o0c = 0.f, o1c = 0.f, o2c = 0.f, o3c = 0.f;
#pragma unroll
    for (int c = 0; c < CPG; ++c) {
      float p0 = rf[c][0] * t[c][(16 + 0 - i) & 3];
      float p1 = rf[c][1] * t[c][(16 + 1 - i) & 3];
      float p2 = rf[c][2] * t[c][(16 + 2 - i) & 3];
      float p3 = rf[c][3] * t[c][(16 + 3 - i) & 3];
      o0h += p0 * al[c]; o0c += p0 * be[c];
      o1h += p1 * al[c]; o1c += p1 * be[c];
      o2h += p2 * al[c]; o2c += p2 * be[c];
      o3h += p3 * al[c]; o3c += p3 * be[c];
    }
    fx4 vh = {o0h, o1h, o2h, o3h};
    fx4 vc = {o0c, o1c, o2c, o3c};
    __builtin_nontemporal_store(vh, reinterpret_cast<fx4*>(out + o_hf));
    __builtin_nontemporal_store(vc, reinterpret_cast<fx4*>(out + o_ct));
    o_hf += HH * WW;
    o_ct += HH * WW;
  }
}

// -------------------------------------------------------------------------
extern "C" void kernel_launch(void* const* d_in, const int* in_sizes, int n_in,
                              void* d_out, int out_size, void* d_ws, size_t ws_size,
                              hipStream_t stream) {
  const float* ref = (const float*)d_in[0];
  const float* tgt = (const float*)d_in[1];
  const float* w1  = (const float*)d_in[2];
  const float* b1  = (const float*)d_in[3];
  const float* w2  = (const float*)d_in[4];
  const float* b2  = (const float*)d_in[5];
  float* out = (float*)d_out;

  float* ws      = (float*)d_ws;
  float* gap     = ws;            // 1280 floats
  float* alpha   = ws + 1280;     // 640
  float* beta    = ws + 1920;     // 640
  unsigned* counter = (unsigned*)(ws + 2560);  // 1

  hipMemsetAsync(counter, 0, sizeof(unsigned), stream);
  gap_mask_kernel<<<2 * BB * CC, 256, 0, stream>>>(ref, tgt, w1, b1, w2, b2,
                                                   gap, alpha, beta, counter);
  volume_kernel<<<BB * GG * 32, 256, 0, stream>>>(ref, tgt, alpha, beta, out);
}

// Round 7
// 65.624 us; speedup vs baseline: 1.5607x; 1.5607x over previous
//
#include <hip/hip_runtime.h>
#include <hip/hip_bf16.h>

#define BB 2
#define CC 320
#define HH 64
#define WW 128
#define MAXDISP 48
#define GG 40
#define CPG 8     // channels per group = C / G
#define CR 20     // C / R

typedef float fx4 __attribute__((ext_vector_type(4)));

// -------------------------------------------------------------------------
// Kernel 1: global average pool over H*W for each (img, b, c) row.
// 1280 blocks. Plain stores; visibility to the next kernel via the normal
// end-of-dispatch L2 flush (same-stream ordering) -- no atomics.
// Also leaves ref/tgt hot in L3 for the volume kernel.
// -------------------------------------------------------------------------
__global__ __launch_bounds__(256) void gap_kernel(
    const float* __restrict__ ref, const float* __restrict__ tgt,
    float* __restrict__ gap /* [2][B][C] */) {
  int bid = blockIdx.x;            // 0 .. 1280
  int img = bid / (BB * CC);       // 0/1
  int rc  = bid - img * (BB * CC); // b*C + c
  const float* src = (img ? tgt : ref) + (size_t)rc * (HH * WW);
  const float4* v = reinterpret_cast<const float4*>(src);
  float acc = 0.f;
  for (int i = threadIdx.x; i < (HH * WW) / 4; i += 256) {
    float4 x = v[i];
    acc += (x.x + x.y) + (x.z + x.w);
  }
  for (int off = 32; off; off >>= 1) acc += __shfl_down(acc, off, 64);
  __shared__ float part[4];
  if ((threadIdx.x & 63) == 0) part[threadIdx.x >> 6] = acc;
  __syncthreads();
  if (threadIdx.x == 0) {
    float s = (part[0] + part[1]) + (part[2] + part[3]);
    gap[bid] = s * (1.0f / (HH * WW));
  }
}

// -------------------------------------------------------------------------
// Kernel 2: correlation volumes with the CMCAM FC stack fused in as a
// per-block prologue (redundant recompute; each block only needs its own
// group's 8 channels x 2 images). FC compute hides under the global->LDS
// staging loads; removes the single-block mask kernel and one launch
// boundary.
//   alpha = m_ref*m_tgt/8, beta = (1-m_ref)(1-m_tgt)/8  (/8 folds group-mean)
// Volume core (unchanged from 65.6 us round): block = (b, g, h2); 256
// threads = dslot(4) x hl(2) x w4(32); register-ring over d; XOR-swizzled
// LDS; float4 nt stores.
// -------------------------------------------------------------------------
__global__ __launch_bounds__(256) void volume_kernel(
    const float* __restrict__ ref, const float* __restrict__ tgt,
    const float* __restrict__ gap /* [2][B][C] */,
    const float* __restrict__ w1, const float* __restrict__ b1,
    const float* __restrict__ w2, const float* __restrict__ b2,
    float* __restrict__ out) {
  __shared__ float Tl[2][CPG][WW];   // 8 KB, x-swizzled
  __shared__ float gsl[2 * CC];      // gap rows for this b: [img][c]
  __shared__ float hsl[2 * CR];      // FC1 out: [img][j]
  __shared__ float abw[2][CPG];      // masks -> alpha/beta

  int bid = blockIdx.x;              // b*(G*32) + g*32 + h2
  int b   = bid / (GG * 32);
  int rem = bid - b * (GG * 32);
  int g   = rem >> 5;
  int h2  = rem & 31;
  int tid = threadIdx.x;
  int dslot = tid >> 6;              // 0..3 (= wave id)
  int hl    = (tid >> 5) & 1;
  int w4    = tid & 31;
  int wq    = w4 << 2;
  int d0    = dslot * 12;
  int h     = h2 * 2 + hl;

  // ---- stage tgt rows -> LDS (swizzled); issue before FC so loads hide
  {
    int c_s = tid >> 5;
    int xq  = (tid & 31) << 2;
    int k   = (xq >> 5) & 3;         // swizzle key, constant over the quad
    size_t tb = ((size_t)((b * CC + g * CPG + c_s) * HH) + h2 * 2) * WW + xq;
    float4 v0 = *reinterpret_cast<const float4*>(tgt + tb);
    float4 v1 = *reinterpret_cast<const float4*>(tgt + tb + WW);
    float4 q0 = (k & 1) ? make_float4(v0.y, v0.x, v0.w, v0.z) : v0;
    q0 = (k & 2) ? make_float4(q0.z, q0.w, q0.x, q0.y) : q0;
    float4 q1 = (k & 1) ? make_float4(v1.y, v1.x, v1.w, v1.z) : v1;
    q1 = (k & 2) ? make_float4(q1.z, q1.w, q1.x, q1.y) : q1;
    *reinterpret_cast<float4*>(&Tl[0][c_s][xq]) = q0;
    *reinterpret_cast<float4*>(&Tl[1][c_s][xq]) = q1;
  }

  // ---- ref quads -> registers
  float rf[CPG][4];
  size_t rbase = ((size_t)((b * CC + g * CPG) * HH) + h) * WW + wq;
#pragma unroll
  for (int c = 0; c < CPG; ++c) {
    float4 rv = *reinterpret_cast<const float4*>(ref + rbase + (size_t)c * (HH * WW));
    rf[c][0] = rv.x; rf[c][1] = rv.y; rf[c][2] = rv.z; rf[c][3] = rv.w;
  }

  // ---- stage this b's gap rows (both images): 640 floats
  for (int i = tid; i < 2 * CC; i += 256) {
    int img = i >= CC;
    gsl[i] = gap[img * (BB * CC) + b * CC + (i - img * CC)];
  }
  __syncthreads();                   // gsl + Tl ready

  // ---- FC1: 40 dot-pairs of length 320; 80 threads = (j, quarter)
  if (tid < 80) {
    int j = tid >> 2, q = tid & 3;
    const float4* wrow = reinterpret_cast<const float4*>(w1 + j * CC) + q * 20;
    const float4* g0 = reinterpret_cast<const float4*>(gsl) + q * 20;
    const float4* g1 = reinterpret_cast<const float4*>(gsl + CC) + q * 20;
    float s0 = 0.f, s1 = 0.f;
#pragma unroll 5
    for (int c2 = 0; c2 < 20; ++c2) {
      float4 a = wrow[c2];
      float4 x0 = g0[c2], x1 = g1[c2];
      s0 += a.x * x0.x + a.y * x0.y + a.z * x0.z + a.w * x0.w;
      s1 += a.x * x1.x + a.y * x1.y + a.z * x1.z + a.w * x1.w;
    }
    s0 += __shfl_xor(s0, 1, 64); s1 += __shfl_xor(s1, 1, 64);
    s0 += __shfl_xor(s0, 2, 64); s1 += __shfl_xor(s1, 2, 64);
    if (q == 0) {
      float t0 = s0 + b1[j];
      float t1 = s1 + b1[j];
      hsl[j]      = t0 > 0.f ? t0 : 0.f;   // ReLU, img 0
      hsl[CR + j] = t1 > 0.f ? t1 : 0.f;   // ReLU, img 1
    }
  }
  __syncthreads();

  // ---- FC2 + sigmoid: only this group's 8 channels x 2 images
  if (tid < 16) {
    int img = tid >> 3, cl = tid & 7;
    int c = g * CPG + cl;
    float s = b2[c];
    const float* wrow = w2 + c * CR;
    const float* hr = hsl + img * CR;
#pragma unroll
    for (int j = 0; j < CR; ++j) s += wrow[j] * hr[j];
    abw[img][cl] = 1.f / (1.f + expf(-s));  // mask
  }
  __syncthreads();
  if (tid < CPG) {                   // masks -> fused alpha/beta (in place)
    float m0 = abw[0][tid], m1 = abw[1][tid];
    abw[0][tid] = m0 * m1 * 0.125f;
    abw[1][tid] = (1.f - m0) * (1.f - m1) * 0.125f;
  }
  __syncthreads();

  float al[CPG], be[CPG];
#pragma unroll
  for (int c = 0; c < CPG; ++c) {
    al[c] = abw[0][c];
    be[c] = abw[1][c];
  }

  // ---- ring prefill: slot r holds tap x = A + r
  const int A = wq - d0;
  float t[CPG][4];
#pragma unroll
  for (int r = 0; r < 4; ++r) {
    int x  = A + r;
    int xc = x < 0 ? 0 : x;
    int xs = xc ^ ((xc >> 5) & 3);
#pragma unroll
    for (int c = 0; c < CPG; ++c) {
      float v = Tl[hl][c][xs];
      t[c][r] = x < 0 ? 0.f : v;
    }
  }

  size_t o_hf = (((size_t)(b * 2 * GG + g) * MAXDISP + d0) * HH + h) * WW + wq;
  size_t o_ct = o_hf + (size_t)GG * MAXDISP * HH * WW;
#pragma unroll
  for (int i = 0; i < 12; ++i) {
    if (i > 0) {                     // slide window: new tap x = A - i
      int x  = A - i;
      int xc = x < 0 ? 0 : x;
      int xs = xc ^ ((xc >> 5) & 3);
      const int s = (16 - i) & 3;    // slot being replaced
#pragma unroll
      for (int c = 0; c < CPG; ++c) {
        float v = Tl[hl][c][xs];
        t[c][s] = x < 0 ? 0.f : v;
      }
    }
    float o0h = 0.f, o1h = 0.f, o2h = 0.f, o3h = 0.f;
    float o0c = 0.f, o1c = 0.f, o2c = 0.f, o3c = 0.f;
#pragma unroll
    for (int c = 0; c < CPG; ++c) {
      float p0 = rf[c][0] * t[c][(16 + 0 - i) & 3];
      float p1 = rf[c][1] * t[c][(16 + 1 - i) & 3];
      float p2 = rf[c][2] * t[c][(16 + 2 - i) & 3];
      float p3 = rf[c][3] * t[c][(16 + 3 - i) & 3];
      o0h += p0 * al[c]; o0c += p0 * be[c];
      o1h += p1 * al[c]; o1c += p1 * be[c];
      o2h += p2 * al[c]; o2c += p2 * be[c];
      o3h += p3 * al[c]; o3c += p3 * be[c];
    }
    fx4 vh = {o0h, o1h, o2h, o3h};
    fx4 vc = {o0c, o1c, o2c, o3c};
    __builtin_nontemporal_store(vh, reinterpret_cast<fx4*>(out + o_hf));
    __builtin_nontemporal_store(vc, reinterpret_cast<fx4*>(out + o_ct));
    o_hf += HH * WW;
    o_ct += HH * WW;
  }
}

// -------------------------------------------------------------------------
extern "C" void kernel_launch(void* const* d_in, const int* in_sizes, int n_in,
                              void* d_out, int out_size, void* d_ws, size_t ws_size,
                              hipStream_t stream) {
  const float* ref = (const float*)d_in[0];
  const float* tgt = (const float*)d_in[1];
  const float* w1  = (const float*)d_in[2];
  const float* b1  = (const float*)d_in[3];
  const float* w2  = (const float*)d_in[4];
  const float* b2  = (const float*)d_in[5];
  float* out = (float*)d_out;
  float* gap = (float*)d_ws;       // 1280 floats

  gap_kernel<<<2 * BB * CC, 256, 0, stream>>>(ref, tgt, gap);
  volume_kernel<<<BB * GG * 32, 256, 0, stream>>>(ref, tgt, gap,
                                                  w1, b1, w2, b2, out);
}